// Round 11
// baseline (78.905 us; speedup 1.0000x reference)
//
#include <hip/hip_runtime.h>

namespace {

constexpr int HIMG = 512;
constexpr int ROWF = 1536;        // floats per image row
constexpr int SH   = 32;          // strip height (output rows per wave)
constexpr int SPANS = 6;          // 256-float spans per row
constexpr int STRIPS = HIMG / SH; // 16
constexpr int LROW = 288;         // LDS floats per wave row (12 + 256 + 12, padded)
constexpr int WPB  = 4;           // waves per block

typedef float vf4 __attribute__((ext_vector_type(4)));

// exp(-x^2/(2*1.5^2)), double precision (matches cv2.getGaussianKernel)
constexpr double KD0 = 0.13533528323661270;  // x=3
constexpr double KD1 = 0.41111229050718745;  // x=2
constexpr double KD2 = 0.80073740291680804;  // x=1
constexpr double KSUM = 1.0 + 2.0 * (KD0 + KD1 + KD2);

__device__ __forceinline__ int reflect_f(int f) {
  int c = f % 3; if (c < 0) c += 3;      // channel
  int p = (f - c) / 3;                   // pixel
  p = p < 0 ? -p : (p > 511 ? 1022 - p : p);  // reflect-101
  return 3 * p + c;
}

__global__ __launch_bounds__(64 * WPB, 6) void gauss7(const float* __restrict__ in,
                                                      float* __restrict__ out) {
  constexpr float W[7] = {
      (float)(KD0 / KSUM), (float)(KD1 / KSUM), (float)(KD2 / KSUM),
      (float)(1.0 / KSUM),
      (float)(KD2 / KSUM), (float)(KD1 / KSUM), (float)(KD0 / KSUM)};

  __shared__ __align__(16) float lds[WPB][LROW];

  // bijective XCD swizzle: 1536 blocks, 8 XCDs -> XCD k owns contiguous 192
  const int bid = blockIdx.x;
  const int b   = (bid & 7) * 192 + (bid >> 3);

  const int wid  = threadIdx.x >> 6;
  const int lane = threadIdx.x & 63;
  const int gw   = b * WPB + wid;            // 0..6143
  const int img  = gw / (SPANS * STRIPS);    // /96
  const int rem  = gw - img * (SPANS * STRIPS);
  const int span = rem >> 4;                 // 0..5
  const int strip= rem & 15;                 // 0..15 (consecutive gw -> adjacent strips)
  const int h0   = strip * SH;
  const int spanf= span << 8;                // 256*span

  const float* inN  = in  + (size_t)img * HIMG * ROWF;
  float*       outN = out + (size_t)img * HIMG * ROWF;
  float* wrow = lds[wid];

  const int ownf = spanf + 4 * lane;         // own float4 column in the row

  // ---- halo lanes: 0,1,2 cover left 12 floats; 61,62,63 cover right 12 ----
  const bool hact = (lane < 3) || (lane >= 61);
  int ldsoff = 0, sf0 = 0, sf1 = 0, sf2 = 0, sf3 = 0;
  if (lane < 3) {
    ldsoff = 4 * lane;                       // LDS floats 0..11
    const int f = spanf - 12 + 4 * lane;     // row float of first element
    sf0 = reflect_f(f);     sf1 = reflect_f(f + 1);
    sf2 = reflect_f(f + 2); sf3 = reflect_f(f + 3);
  } else if (lane >= 61) {
    ldsoff = 268 + 4 * (lane - 61);          // LDS floats 268..279
    const int f = spanf + 256 + 4 * (lane - 61);
    sf0 = reflect_f(f);     sf1 = reflect_f(f + 1);
    sf2 = reflect_f(f + 2); sf3 = reflect_f(f + 3);
  }

  auto loadrow = [&](int r, float4& own, float4& hal) {
    const int rr = r < 0 ? -r : (r > 511 ? 1022 - r : r);   // reflect-101 in H
    const float* rp = inN + (size_t)rr * ROWF;
    own = *reinterpret_cast<const float4*>(rp + ownf);
    if (hact) {                       // 4 masked scalar loads (6/64 lanes)
      hal.x = rp[sf0]; hal.y = rp[sf1]; hal.z = rp[sf2]; hal.w = rp[sf3];
    }
  };

  // ---- streaming loop: rows h0-3 .. h0+SH+2, no barriers anywhere ----
  float4 win0{}, win1{}, win2{}, win3{}, win4{}, win5{};
  float4 curo, curh{}, nxto, nxth{};
  loadrow(h0 - 3, curo, curh);

  const int rlast = h0 + SH + 2;
  for (int r = h0 - 3; r <= rlast; ++r) {
    if (r < rlast) loadrow(r + 1, nxto, nxth);   // 1-deep prefetch, flies under LDS+VALU

    // wave-private LDS stage (wave-synchronous: no cross-wave sharing)
    *reinterpret_cast<float4*>(wrow + 12 + 4 * lane) = curo;
    if (hact) *reinterpret_cast<float4*>(wrow + ldsoff) = curh;
    asm volatile("" ::: "memory");   // keep reads after writes

    // horizontal blur: 7 x b128 window (LDS float k = row float spanf-12+4l+k)
    float s[28];
#pragma unroll
    for (int j = 0; j < 7; ++j)
      *reinterpret_cast<float4*>(&s[4 * j]) =
          *reinterpret_cast<const float4*>(wrow + 4 * lane + 4 * j);
    float4 hb;
    hb.x = W[0]*s[3] + W[1]*s[6] + W[2]*s[9]  + W[3]*s[12] + W[4]*s[15] + W[5]*s[18] + W[6]*s[21];
    hb.y = W[0]*s[4] + W[1]*s[7] + W[2]*s[10] + W[3]*s[13] + W[4]*s[16] + W[5]*s[19] + W[6]*s[22];
    hb.z = W[0]*s[5] + W[1]*s[8] + W[2]*s[11] + W[3]*s[14] + W[4]*s[17] + W[5]*s[20] + W[6]*s[23];
    hb.w = W[0]*s[6] + W[1]*s[9] + W[2]*s[12] + W[3]*s[15] + W[4]*s[18] + W[5]*s[21] + W[6]*s[24];

    // vertical blur from 6-deep register window + hb (taps ascending, rows r-6..r)
    if (r >= h0 + 3) {
      vf4 o;
      o[0] = W[0]*win0.x + W[1]*win1.x + W[2]*win2.x + W[3]*win3.x +
             W[4]*win4.x + W[5]*win5.x + W[6]*hb.x;
      o[1] = W[0]*win0.y + W[1]*win1.y + W[2]*win2.y + W[3]*win3.y +
             W[4]*win4.y + W[5]*win5.y + W[6]*hb.y;
      o[2] = W[0]*win0.z + W[1]*win1.z + W[2]*win2.z + W[3]*win3.z +
             W[4]*win4.z + W[5]*win5.z + W[6]*hb.z;
      o[3] = W[0]*win0.w + W[1]*win1.w + W[2]*win2.w + W[3]*win3.w +
             W[4]*win4.w + W[5]*win5.w + W[6]*hb.w;
      vf4* orow = reinterpret_cast<vf4*>(outN + (size_t)(r - 3) * ROWF + spanf);
      __builtin_nontemporal_store(o, orow + lane);
    }
    win0 = win1; win1 = win2; win2 = win3; win3 = win4; win4 = win5; win5 = hb;
    curo = nxto; curh = nxth;
  }
}

}  // namespace

extern "C" void kernel_launch(void* const* d_in, const int* in_sizes, int n_in,
                              void* d_out, int out_size, void* d_ws, size_t ws_size,
                              hipStream_t stream) {
  const float* x = (const float*)d_in[0];
  float*       y = (float*)d_out;
  dim3 grid(64 * SPANS * STRIPS / WPB);   // 1536 blocks x 4 waves = 6144 strips
  dim3 block(64 * WPB);
  hipLaunchKernelGGL(gauss7, grid, block, 0, stream, x, y);
}